// Round 6
// baseline (478.607 us; speedup 1.0000x reference)
//
#include <hip/hip_runtime.h>
#include <hip/hip_bf16.h>
#include <math.h>

#define B_   4
#define T_   2048
#define C_   2048
#define NH_  16
#define HD_  128
#define KVD_ 1024

typedef __attribute__((ext_vector_type(4))) float f32x4;
typedef __attribute__((ext_vector_type(16))) float f32x16;
typedef __attribute__((ext_vector_type(8))) short bf16x8;
typedef __attribute__((ext_vector_type(4))) unsigned int u32x4;

__device__ __forceinline__ void async_copy16(const __hip_bfloat16* g, __hip_bfloat16* l) {
  __builtin_amdgcn_global_load_lds((const __attribute__((address_space(1))) void*)g,
                                   (__attribute__((address_space(3))) void*)l,
                                   16, 0, 0);
}

__device__ __forceinline__ float bf2f(__hip_bfloat16 h) { return __bfloat162float(h); }

// pack two f32 -> one dword of 2 bf16 (a in low half)
__device__ __forceinline__ unsigned int pkbf(float a, float b) {
  float2 f2; f2.x = a; f2.y = b;
  __hip_bfloat162 h2 = __float22bfloat162_rn(f2);
  return *reinterpret_cast<unsigned int*>(&h2);
}

// ---------------- f32 -> bf16 convert (x) ----------------
__global__ __launch_bounds__(256) void f32_to_bf16_k(const float* __restrict__ src,
                                                     __hip_bfloat16* __restrict__ dst, int n4) {
  int i = blockIdx.x * 256 + threadIdx.x;
  if (i >= n4) return;
  float4 f = ((const float4*)src)[i];
  __hip_bfloat16 o[4] = {__float2bfloat16(f.x), __float2bfloat16(f.y),
                         __float2bfloat16(f.z), __float2bfloat16(f.w)};
  *(uint2*)(dst + (size_t)i * 4) = *(uint2*)o;
}

// ---------------- transpose + convert: WT[n][k] = bf16(W[k][n]) ----------------
__global__ __launch_bounds__(256) void transpose_f32_bf16_k(const float* __restrict__ W,
                                                            __hip_bfloat16* __restrict__ WT,
                                                            int K, int N) {
  __shared__ float tile[32][33];
  int bx = blockIdx.x * 32;  // n
  int by = blockIdx.y * 32;  // k
  int tx = threadIdx.x, ty = threadIdx.y;
  for (int i = ty; i < 32; i += 8)
    tile[i][tx] = W[(size_t)(by + i) * N + (bx + tx)];
  __syncthreads();
  for (int i = ty; i < 32; i += 8)
    WT[(size_t)(bx + i) * K + (by + tx)] = __float2bfloat16(tile[tx][i]);
}

// ---------------- V transpose: Vt[b][g][d][perm(t)] = kv[b][t][512 + g*128 + d] --------
// perm swaps bits 2<->3 of t within each 16-group (see attn_k P layout).
__global__ __launch_bounds__(256) void vtrans_k(const __hip_bfloat16* __restrict__ kv,
                                                __hip_bfloat16* __restrict__ vt) {
  __shared__ __hip_bfloat16 tile[32][33];
  int bg = blockIdx.z;            // b*4+g
  int d0 = blockIdx.y * 32;
  int t0 = blockIdx.x * 32;
  int tx = threadIdx.x, ty = threadIdx.y;
  int b = bg >> 2, g = bg & 3;
  const __hip_bfloat16* src = kv + (size_t)b * T_ * KVD_ + 512 + g * HD_;
  for (int i = ty; i < 32; i += 8)
    tile[i][tx] = src[(size_t)(t0 + i) * KVD_ + d0 + tx];
  __syncthreads();
  __hip_bfloat16* dst = vt + (size_t)bg * HD_ * T_;
  int txp = (tx & ~12) | ((tx & 4) << 1) | ((tx & 8) >> 1);  // swap bits 2,3
  for (int i = ty; i < 32; i += 8)
    dst[(size_t)(d0 + i) * T_ + t0 + txp] = tile[tx][i];
}

// ---------------- row l2norm (in place, bf16), scale folded via `extra` ----------------
template<int PER>
__global__ __launch_bounds__(256) void rownorm_k(__hip_bfloat16* __restrict__ buf,
                                                 int stride, float extra) {
  const int tid = threadIdx.x;
  __hip_bfloat16* p = buf + (size_t)blockIdx.x * stride;
  float v[PER];
  float ss = 0.f;
  #pragma unroll
  for (int e = 0; e < PER; ++e) { v[e] = bf2f(p[tid + e * 256]); ss += v[e] * v[e]; }
  #pragma unroll
  for (int off = 32; off >= 1; off >>= 1) ss += __shfl_xor(ss, off, 64);
  __shared__ float wsum[4];
  if ((tid & 63) == 0) wsum[tid >> 6] = ss;
  __syncthreads();
  float tot = wsum[0] + wsum[1] + wsum[2] + wsum[3];
  float sc = extra / (sqrtf(tot) + 1e-12f);
  #pragma unroll
  for (int e = 0; e < PER; ++e) p[tid + e * 256] = __float2bfloat16(v[e] * sc);
}

// ---------------- GEMM v2: ring-3 LDS, counted-vmcnt pipeline (unchanged from R5) ------
template<typename OutT>
__global__ __launch_bounds__(512, 2) void gemm3_k(const __hip_bfloat16* __restrict__ A,
                                                  const __hip_bfloat16* __restrict__ BT,
                                                  OutT* __restrict__ Cc,
                                                  int M, int N, int K) {
  __shared__ alignas(16) __hip_bfloat16 As[3][128 * 64];
  __shared__ alignas(16) __hip_bfloat16 Bs[3][256 * 64];
  const int tid  = threadIdx.x;
  const int bm   = blockIdx.y * 128;
  const int bn   = blockIdx.x * 256;
  const int wave = tid >> 6, lane = tid & 63;
  const int wm = wave >> 2, wn = wave & 3;
  const int lm = lane & 15, quad = lane >> 4;
  const size_t Kz = (size_t)K;
  const int NT = K >> 6;

  const int srow = tid >> 3;                        // 0..63
  const int csw  = ((tid & 7) ^ (srow & 7)) * 8;    // swizzled 16B chunk offset
  const __hip_bfloat16* aSrc0 = A  + (size_t)(bm + srow) * Kz + csw;
  const __hip_bfloat16* aSrc1 = A  + (size_t)(bm + 64 + srow) * Kz + csw;
  const __hip_bfloat16* bSrc0 = BT + (size_t)(bn + srow) * Kz + csw;
  const __hip_bfloat16* bSrc1 = BT + (size_t)(bn + 64 + srow) * Kz + csw;
  const __hip_bfloat16* bSrc2 = BT + (size_t)(bn + 128 + srow) * Kz + csw;
  const __hip_bfloat16* bSrc3 = BT + (size_t)(bn + 192 + srow) * Kz + csw;

  auto stageA = [&](int slot, int koff) {
    async_copy16(aSrc0 + koff, As[slot] + tid * 8);
    async_copy16(aSrc1 + koff, As[slot] + (512 + tid) * 8);
  };
  auto stageB0 = [&](int slot, int koff) {
    async_copy16(bSrc0 + koff, Bs[slot] + tid * 8);
  };
  auto stageB123 = [&](int slot, int koff) {
    async_copy16(bSrc1 + koff, Bs[slot] + (512 + tid) * 8);
    async_copy16(bSrc2 + koff, Bs[slot] + (1024 + tid) * 8);
    async_copy16(bSrc3 + koff, Bs[slot] + (1536 + tid) * 8);
  };

  const int ch0 = ((quad) ^ (lm & 7)) * 8;
  const int ch1 = ((4 + quad) ^ (lm & 7)) * 8;
  const int arow = wm * 64 + lm;
  const int brow = wn * 64 + lm;

  f32x4 acc[4][4] = {};

  stageA(0, 0); stageB0(0, 0); stageB123(0, 0);
  if (NT > 1) { stageA(1, 64); stageB0(1, 64); stageB123(1, 64); }

  int s = 0;
  for (int t = 0; t < NT; ++t) {
    const int sn = (s + 2 > 2) ? (s - 1) : (s + 2);   // (s+2)%3
    const bool pre = (t + 2) < NT;
    const int koff = (t + 2) * 64;
    if (t + 1 < NT) asm volatile("s_waitcnt vmcnt(6)" ::: "memory");
    else            asm volatile("s_waitcnt vmcnt(0)" ::: "memory");
    __builtin_amdgcn_s_barrier();
    bf16x8 af[4][2], bf0[2][2];
    #pragma unroll
    for (int mf = 0; mf < 4; ++mf) {
      af[mf][0] = *(const bf16x8*)(As[s] + (arow + mf * 16) * 64 + ch0);
      af[mf][1] = *(const bf16x8*)(As[s] + (arow + mf * 16) * 64 + ch1);
    }
    #pragma unroll
    for (int nf = 0; nf < 2; ++nf) {
      bf0[nf][0] = *(const bf16x8*)(Bs[s] + (brow + nf * 16) * 64 + ch0);
      bf0[nf][1] = *(const bf16x8*)(Bs[s] + (brow + nf * 16) * 64 + ch1);
    }
    if (pre) { stageA(sn, koff); stageB0(sn, koff); }
    __builtin_amdgcn_s_barrier();
    __builtin_amdgcn_s_setprio(1);
    #pragma unroll
    for (int mf = 0; mf < 4; ++mf)
      #pragma unroll
      for (int nf = 0; nf < 2; ++nf) {
        acc[mf][nf] = __builtin_amdgcn_mfma_f32_16x16x32_bf16(af[mf][0], bf0[nf][0], acc[mf][nf], 0, 0, 0);
        acc[mf][nf] = __builtin_amdgcn_mfma_f32_16x16x32_bf16(af[mf][1], bf0[nf][1], acc[mf][nf], 0, 0, 0);
      }
    __builtin_amdgcn_s_setprio(0);
    __builtin_amdgcn_s_barrier();
    bf16x8 bf1[2][2];
    #pragma unroll
    for (int nf = 0; nf < 2; ++nf) {
      bf1[nf][0] = *(const bf16x8*)(Bs[s] + (brow + (nf + 2) * 16) * 64 + ch0);
      bf1[nf][1] = *(const bf16x8*)(Bs[s] + (brow + (nf + 2) * 16) * 64 + ch1);
    }
    if (pre) stageB123(sn, koff);
    __builtin_amdgcn_s_barrier();
    __builtin_amdgcn_s_setprio(1);
    #pragma unroll
    for (int mf = 0; mf < 4; ++mf)
      #pragma unroll
      for (int nf = 0; nf < 2; ++nf) {
        acc[mf][nf + 2] = __builtin_amdgcn_mfma_f32_16x16x32_bf16(af[mf][0], bf1[nf][0], acc[mf][nf + 2], 0, 0, 0);
        acc[mf][nf + 2] = __builtin_amdgcn_mfma_f32_16x16x32_bf16(af[mf][1], bf1[nf][1], acc[mf][nf + 2], 0, 0, 0);
      }
    __builtin_amdgcn_s_setprio(0);
    s = (s == 2) ? 0 : s + 1;
  }

  const int r0 = quad * 4;
  #pragma unroll
  for (int mf = 0; mf < 4; ++mf)
    #pragma unroll
    for (int nf = 0; nf < 4; ++nf)
      #pragma unroll
      for (int r = 0; r < 4; ++r) {
        int gr = bm + wm * 64 + mf * 16 + r0 + r;
        int gc = bn + wn * 64 + nf * 16 + lm;
        float v = acc[mf][nf][r];
        if constexpr (__is_same(OutT, float))
          Cc[(size_t)gr * N + gc] = v;
        else
          Cc[(size_t)gr * N + gc] = __float2bfloat16(v);
      }
}

// ---------------- flash attention v7: triangle fold + kv-split wave pairs ----------------
// 512 threads = 8 waves. Waves w and w+4 process the SAME 32 q-rows (wq = w&3) but
// opposite 32-kv halves of each 64-row K-tile (grp = w>>2). Each wave's per-tile chain
// halves (8+8 MFMA); total waves double -> 16 waves/CU (4/SIMD) at the same 64 KB LDS.
// Group B's path is bit-identical to the old st1 / kc{2,3} path. Partial O and l are
// combined through LDS buffer-1 (free after the loop; prefetch uses buffer 0) in two
// 32 KB rounds. __launch_bounds__(512,2): 2 blocks/CU -> 128-VGPR cap (fits ~125 live).
__global__ __launch_bounds__(512, 2) void attn_k(const __hip_bfloat16* __restrict__ q,
                                                 const __hip_bfloat16* __restrict__ kv,
                                                 const __hip_bfloat16* __restrict__ vt,
                                                 __hip_bfloat16* __restrict__ y) {
  const int pp = blockIdx.x;      // pair index 0..7
  const int h  = blockIdx.y;
  const int b  = blockIdx.z;
  const int g  = h >> 2;
  const int tid = threadIdx.x;
  const int wave = tid >> 6, lane = tid & 63;
  const int l31 = lane & 31, hi = lane >> 5;
  const int wq = wave & 3;        // q sub-tile within block
  const int grp = wave >> 2;      // 0: kv rows 0-31, 1: kv rows 32-63
  const int kvofs = grp * 32;

  __shared__ alignas(16) __hip_bfloat16 Ks[2][64 * 128];
  __shared__ alignas(16) __hip_bfloat16 Vts[2][128 * 64];

  const __hip_bfloat16* kb = kv + (size_t)b * T_ * KVD_ + g * HD_;
  const __hip_bfloat16* vb = vt + (size_t)(b * 4 + g) * HD_ * T_;

  auto stage = [&](int buf, int jt) {
    const size_t j1 = (size_t)jt * 64;
    #pragma unroll
    for (int e = 0; e < 2; ++e) {
      int idx = tid + e * 512;
      int row = idx >> 4, c = idx & 15;
      async_copy16(kb + (j1 + row) * KVD_ + ((c ^ (row & 15)) * 8), Ks[buf] + idx * 8);
    }
    #pragma unroll
    for (int e = 0; e < 2; ++e) {
      int idx = tid + e * 512;
      int row = idx >> 3, c = idx & 7;
      async_copy16(vb + (size_t)row * T_ + j1 + ((c ^ (row & 7)) * 8), Vts[buf] + idx * 8);
    }
  };

  stage(0, 0);  // first tile of first segment

  #pragma unroll
  for (int seg = 0; seg < 2; ++seg) {
    const int qt = seg ? pp : (15 - pp);
    const int qbase = qt * 128 + wq * 32;
    const int qmax = qbase + 31;
    const int ntiles = 2 * qt + 2;  // always even -> last tile uses buffer 1

    // Q -> registers (one row per lane&31; hi half picks the 8-elem sub-chunk)
    const __hip_bfloat16* qrow = q + ((size_t)b * T_ + qbase + l31) * C_ + h * HD_;
    bf16x8 qf[8];
    #pragma unroll
    for (int kc = 0; kc < 8; ++kc)
      qf[kc] = *(const bf16x8*)(qrow + kc * 16 + hi * 8);

    __syncthreads();  // tile 0 of this segment staged (barrier drains vmcnt)

    f32x16 o_acc[4] = {};
    float l_acc = 0.f;

    for (int it = 0; it < ntiles; ++it) {
      const int cur = it & 1;
      if (it + 1 < ntiles) stage(cur ^ 1, it + 1);
      const int j0k = it * 64 + kvofs;   // this wave's kv-half base
      if (j0k <= qmax) {  // wave-uniform: skip fully-masked halves
        // ---- S^T = K Q^T on this wave's 32 kv rows ----
        f32x16 st = {};
        __builtin_amdgcn_s_setprio(1);
        #pragma unroll
        for (int kc = 0; kc < 8; ++kc) {
          const int cs0 = (((2 * kc + hi) ^ (l31 & 15)) * 8);
          bf16x8 kf = *(const bf16x8*)(Ks[cur] + (kvofs + l31) * 128 + cs0);
          st = __builtin_amdgcn_mfma_f32_32x32x16_bf16(kf, qf[kc], st, 0, 0, 0);
        }
        __builtin_amdgcn_s_setprio(0);
        // ---- P = exp(S) + causal mask; per-lane only (q row = lane&31) ----
        const int qd = qbase + l31 - j0k;  // kv_local <= qd is unmasked
        if (j0k + 31 <= qbase) {           // half fully unmasked: skip compares
          #pragma unroll
          for (int r = 0; r < 16; ++r) {
            float p0 = __expf(st[r]);
            st[r] = p0;
            l_acc += p0;
          }
        } else {
          #pragma unroll
          for (int r = 0; r < 16; ++r) {
            const int ofs = (r & 3) + 8 * (r >> 2) + 4 * hi;  // kv_local 0..31
            float p0 = (ofs <= qd) ? __expf(st[r]) : 0.f;
            st[r] = p0;
            l_acc += p0;
          }
        }
        // ---- pack P -> bf16 words W[m][i]; m = local kv-group (8 kv) ----
        unsigned int W[4][2];
        #pragma unroll
        for (int q4 = 0; q4 < 4; ++q4) {
          W[q4][0] = pkbf(st[4 * q4 + 0], st[4 * q4 + 1]);
          W[q4][1] = pkbf(st[4 * q4 + 2], st[4 * q4 + 3]);
        }
        // ---- O += P V on this wave's kv half (kc = grp*2 + kci) ----
        __builtin_amdgcn_s_setprio(1);
        #pragma unroll
        for (int kci = 0; kci < 2; ++kci) {
          const int kc = grp * 2 + kci;
          u32x4 pw;
          pw[0] = W[2 * kci][0]; pw[1] = W[2 * kci][1];
          pw[2] = W[2 * kci + 1][0]; pw[3] = W[2 * kci + 1][1];
          bf16x8 pf = __builtin_bit_cast(bf16x8, pw);
          const int csv = (((2 * kc + hi) ^ (l31 & 7)) * 8);
          #pragma unroll
          for (int ct = 0; ct < 4; ++ct) {
            bf16x8 vf = *(const bf16x8*)(Vts[cur] + (ct * 32 + l31) * 64 + csv);
            o_acc[ct] = __builtin_amdgcn_mfma_f32_32x32x16_bf16(pf, vf, o_acc[ct], 0, 0, 0);
          }
        }
        __builtin_amdgcn_s_setprio(0);
      }
      __syncthreads();  // drains prefetch vmcnt + protects buffer swap
    }

    // prefetch next segment's tile 0 into BUFFER 0 (combine uses buffer 1 only)
    if (seg == 0) stage(0, 0);

    // ---- combine wave-pair partials through LDS buffer 1 ----
    float lsum = l_acc + __shfl_xor(l_acc, 32, 64);  // both hi halves of this wave
    float* lcomb = (float*)&Ks[1][0];
    float* r0 = (float*)&Ks[1][0];    // 16 KB region
    float* r1 = (float*)&Vts[1][0];   // 16 KB region
    if (grp == 1) lcomb[wq * 64 + lane] = lsum;
    __syncthreads();
    if (grp == 0) lsum += lcomb[wq * 64 + lane];
    __syncthreads();

    float oinv[16];
    if (grp == 0) {
      #pragma unroll
      for (int r = 0; r < 16; ++r) {
        int row = (r & 3) + 8 * (r >> 2) + 4 * hi;
        oinv[r] = 1.0f / __shfl(lsum, row, 64);
      }
    }
    __hip_bfloat16* yb = y + ((size_t)b * T_ + qbase) * C_ + h * HD_ + l31;
    #pragma unroll
    for (int rd = 0; rd < 2; ++rd) {
      const int c0 = rd * 2;
      if (grp == 1) {
        *(f32x16*)(r0 + (wq * 64 + lane) * 16) = o_acc[c0];
        *(f32x16*)(r1 + (wq * 64 + lane) * 16) = o_acc[c0 + 1];
      }
      __syncthreads();
      if (grp == 0) {
        f32x16 p0 = *(const f32x16*)(r0 + (wq * 64 + lane) * 16);
        f32x16 p1 = *(const f32x16*)(r1 + (wq * 64 + lane) * 16);
        #pragma unroll
        for (int r = 0; r < 16; ++r) {
          int row = (r & 3) + 8 * (r >> 2) + 4 * hi;
          yb[(size_t)row * C_ + c0 * 32] =
              __float2bfloat16((o_acc[c0][r] + p0[r]) * oinv[r]);
          yb[(size_t)row * C_ + (c0 + 1) * 32] =
              __float2bfloat16((o_acc[c0 + 1][r] + p1[r]) * oinv[r]);
        }
      }
      __syncthreads();
    }
  }
}

extern "C" void kernel_launch(void* const* d_in, const int* in_sizes, int n_in,
                              void* d_out, int out_size, void* d_ws, size_t ws_size,
                              hipStream_t stream) {
  (void)in_sizes; (void)n_in; (void)out_size; (void)ws_size;
  const float* x     = (const float*)d_in[0];
  const float* Wq    = (const float*)d_in[1];
  const float* Wkv   = (const float*)d_in[2];
  const float* Wproj = (const float*)d_in[3];
  char* ws = (char*)d_ws;
  __hip_bfloat16* xb     = (__hip_bfloat16*)(ws);               // 32 MB (reused as y)
  __hip_bfloat16* WqT    = (__hip_bfloat16*)(ws + 33554432);    //  8 MB
  __hip_bfloat16* WkvT   = (__hip_bfloat16*)(ws + 41943040);    //  4 MB
  __hip_bfloat16* WprojT = (__hip_bfloat16*)(ws + 46137344);    //  8 MB
  __hip_bfloat16* qn     = (__hip_bfloat16*)(ws + 54525952);    // 32 MB
  __hip_bfloat16* kvb    = (__hip_bfloat16*)(ws + 88080384);    // 16 MB
  __hip_bfloat16* y      = xb;                                  // alias: xb dead after kv-gemm
  __hip_bfloat16* vt     = (__hip_bfloat16*)d_out;              // 16 MB scratch in d_out
  float* out             = (float*)d_out;

  f32_to_bf16_k<<<16384, 256, 0, stream>>>(x, xb, 4194304);
  transpose_f32_bf16_k<<<dim3(64, 64), dim3(32, 8), 0, stream>>>(Wq, WqT, 2048, 2048);
  transpose_f32_bf16_k<<<dim3(32, 64), dim3(32, 8), 0, stream>>>(Wkv, WkvT, 2048, 1024);
  transpose_f32_bf16_k<<<dim3(64, 64), dim3(32, 8), 0, stream>>>(Wproj, WprojT, 2048, 2048);
  gemm3_k<__hip_bfloat16><<<dim3(8, 64), 512, 0, stream>>>(xb, WqT, qn, 8192, 2048, 2048);
  gemm3_k<__hip_bfloat16><<<dim3(4, 64), 512, 0, stream>>>(xb, WkvT, kvb, 8192, 1024, 2048);
  rownorm_k<8><<<8192, 256, 0, stream>>>(qn, 2048, 0.08838834764831845f);  // 1/sqrt(HD) folded
  rownorm_k<2><<<8192, 256, 0, stream>>>(kvb, 1024, 1.0f);
  vtrans_k<<<dim3(64, 4, 16), dim3(32, 8), 0, stream>>>(kvb, vt);
  attn_k<<<dim3(8, 16, 4), 512, 0, stream>>>(qn, kvb, vt, y);
  gemm3_k<float><<<dim3(8, 64), 512, 0, stream>>>(y, WprojT, out, 8192, 2048, 2048);
}